// Round 11
// baseline (693.543 us; speedup 1.0000x reference)
//
#include <hip/hip_runtime.h>
#include <hip/hip_bf16.h>
#include <hip/hip_cooperative_groups.h>

namespace cg = cooperative_groups;

// GraphSAGE 2-layer, N=100K, E=1.6M, 128->128(relu)->64, log_softmax. fp32 in/out.
//
//   k0: Wf repack + bcount zero                 (1 dispatch, tiny)
//   k1: bucket_scatter || proj1                 (r17 verbatim, 46us, scatter hidden)
//   kc: CSR -> gsync -> agg_relu -> gsync -> proj2 -> gsync -> agg_lsm (cooperative)
//
// r18: dispatch-count attack. 9 rounds flat at 242-247; kernel sum ~160us but total
// 247 -> ~85us is inter-dispatch overhead (7 boundaries x ~11us). Fuse the dependent
// chain into ONE cooperative kernel (grid.sync between stages; bodies verbatim from
// measured-best forms, grid-stride loops). 7 dispatches -> 3. Grid = 3 blocks/CU
// (launch_bounds(512,6), 32KB dyn LDS) = 768, validated via occupancy API.

typedef __attribute__((ext_vector_type(8))) short short8;   // 8 x bf16 = 4 VGPRs
typedef __attribute__((ext_vector_type(4))) float f32x4;
typedef __attribute__((ext_vector_type(2))) float f32x2;

#define NPB 512          // nodes per bucket (dst >> 9)
#define BCAP 16384       // edge capacity per bucket (padded mean ~11.8K)
#define CHUNK 8192       // edges per bucket_scatter block

__device__ __forceinline__ ushort f2bf(float f) {           // round-to-nearest-even
    unsigned u = __float_as_uint(f);
    return (ushort)((u + 0x7fff + ((u >> 16) & 1)) >> 16);
}
__device__ __forceinline__ float bflo(unsigned v) { return __uint_as_float(v << 16); }
__device__ __forceinline__ float bfhi(unsigned v) { return __uint_as_float(v & 0xffff0000u); }
__device__ __forceinline__ unsigned pk4bf(float a, float b) {   // 1 VOP3 (RNE)
    unsigned r;
    asm("v_cvt_pk_bf16_f32 %0, %1, %2" : "=v"(r) : "v"(a), "v"(b));
    return r;
}
__device__ __forceinline__ f32x2 pkadd(f32x2 a, f32x2 b) {      // 1 VOP3P (2xf32 add)
    f32x2 r;
    asm("v_pk_add_f32 %0, %1, %2" : "=v"(r) : "v"(a), "v"(b));
    return r;
}
__device__ __forceinline__ f32x2 shflx2(f32x2 v, int m) {
    f32x2 r; r[0] = __shfl_xor(v[0], m); r[1] = __shfl_xor(v[1], m); return r;
}

// ---------- weight repack into MFMA fragment order ---------------------------------
// Wf idx = ((ct*16 + kc)*16 + m)*8 + j holds W[k=kc*8+j][c=ct*16+m]
__device__ __forceinline__ void wfrag_one(const float* W, ushort* Wf, int i, int COLS) {
    int j = i & 7, m = (i >> 3) & 15, kc = (i >> 7) & 15, ct = i >> 11;
    Wf[i] = f2bf(W[(kc * 8 + j) * COLS + ct * 16 + m]);
}

// ---------- k0: weight repack (49152 elements, 96 blocks) + bcount zero ------------
__global__ void __launch_bounds__(512)
k0_cvtw(const float* __restrict__ Wl1, const float* __restrict__ Wr1,
        const float* __restrict__ Wl2, const float* __restrict__ Wr2,
        ushort* __restrict__ Wf_l1, ushort* __restrict__ Wf_r1,
        ushort* __restrict__ Wf_l2, ushort* __restrict__ Wf_r2,
        int* __restrict__ bcount, int NB) {
    int tid = (int)threadIdx.x;
    if (blockIdx.x == 0 && tid < NB) bcount[tid] = 0;
    int i = (int)blockIdx.x * 512 + tid;
    if (i < 16384)       wfrag_one(Wl1, Wf_l1, i, 128);
    else if (i < 32768)  wfrag_one(Wr1, Wf_r1, i - 16384, 128);
    else if (i < 40960)  wfrag_one(Wl2, Wf_l2, i - 32768, 64);
    else if (i < 49152)  wfrag_one(Wr2, Wf_r2, i - 40960, 64);
}

// ---------- stage both weight fragment arrays into LDS (linear copy, 512 thr) ------
template <int CTOT>
__device__ __forceinline__ void stage_weights(const ushort* __restrict__ Wfl,
                                              const ushort* __restrict__ Wfr,
                                              ushort* dst, int tid) {
    constexpr int HALF = CTOT / 2;            // ushorts per matrix
    constexpr int ITERS = (CTOT * 2) / 8192;  // 512 thr * 16B per iter
#pragma unroll
    for (int r = 0; r < ITERS; ++r) {
        int u = r * 4096 + tid * 8;           // ushort index; half uniform per r
        const ushort* s = (u < HALF) ? (Wfl + u) : (Wfr + (u - HALF));
        *(short8*)(dst + u) = *(const short8*)s;
    }
}

// ---------- projection tile: p = fp8(X@Wl), q = bf16(X@Wr + b), W already in LDS ---
// Operand-swapped MFMA; 512 threads, 8 waves x 16 rows. Row N = zero sentinel.
template <int COLS, bool F32IN>
__device__ __forceinline__ void proj_tile(int bid, int tid,
                            const void* __restrict__ xin,
                            const ushort* Wl, const ushort* Wr,
                            const float* __restrict__ bias,
                            unsigned char* __restrict__ p8, ushort* __restrict__ q, int N) {
    constexpr int CT = COLS / 16;
    int wave = tid >> 6, lane = tid & 63;
    int quad = lane >> 4, m = lane & 15;
    long row0 = (long)bid * 128 + wave * 16;
    long node = row0 + m;
    long arow = (node < N) ? node : (N - 1);

    f32x4 accp[CT], accq[CT];
#pragma unroll
    for (int ct = 0; ct < CT; ++ct) { accp[ct] = (f32x4)0.0f; accq[ct] = (f32x4)0.0f; }

#pragma unroll
    for (int kk = 0; kk < 128; kk += 32) {
        short8 b;                            // B-frag: B[k][n=lane&15] = x[node][k]
        if (F32IN) {
            const float* xf = (const float*)xin + arow * 128 + kk + quad * 8;
            float4 f0 = *(const float4*)xf;
            float4 f1 = *(const float4*)(xf + 4);
            union { short8 s; unsigned u[4]; } bu;
            bu.u[0] = pk4bf(f0.x, f0.y); bu.u[1] = pk4bf(f0.z, f0.w);
            bu.u[2] = pk4bf(f1.x, f1.y); bu.u[3] = pk4bf(f1.z, f1.w);
            b = bu.s;
        } else {
            b = *(const short8*)((const ushort*)xin + arow * 128 + kk + quad * 8);
        }
        int kc = (kk >> 3) + quad;
#pragma unroll
        for (int ct = 0; ct < CT; ++ct) {
            int boff = ((ct * 16 + kc) * 16 + m) * 8;      // 32-bit LDS addressing
            short8 al = *(const short8*)(Wl + boff);       // ds_read_b128
            short8 ar = *(const short8*)(Wr + boff);
            accp[ct] = __builtin_amdgcn_mfma_f32_16x16x32_bf16(al, b, accp[ct], 0, 0, 0);
            accq[ct] = __builtin_amdgcn_mfma_f32_16x16x32_bf16(ar, b, accq[ct], 0, 0, 0);
        }
    }

    if (node <= N) {                          // row N = zero sentinel
        unsigned msk = (node == N) ? 0u : ~0u;
#pragma unroll
        for (int ct = 0; ct < CT; ++ct) {
            int c0 = ct * 16 + quad * 4;
            float4 bv = *(const float4*)(bias + c0);
            float q0 = accq[ct][0] + bv.x, q1 = accq[ct][1] + bv.y;
            float q2 = accq[ct][2] + bv.z, q3 = accq[ct][3] + bv.w;
            unsigned w = (unsigned)__builtin_amdgcn_cvt_pk_fp8_f32(accp[ct][0], accp[ct][1], 0, false);
            w = (unsigned)__builtin_amdgcn_cvt_pk_fp8_f32(accp[ct][2], accp[ct][3], (int)w, true);
            *(unsigned*)(p8 + node * COLS + c0) = w & msk;
            uint2 qw; qw.x = pk4bf(q0, q1) & msk; qw.y = pk4bf(q2, q3) & msk;
            *(uint2*)(q + node * COLS + c0) = qw;
        }
    }
}

// ---------- K1: bucket_scatter (blocks 0..NSC) || proj1 (rest) [r17 verbatim] ------
__global__ void __launch_bounds__(512, 4)
k1_scatter_proj1(const int* __restrict__ src, const int* __restrict__ dst,
                 int* __restrict__ bcount, unsigned* __restrict__ bbuf,
                 int E, int NSC, int N,
                 const float* __restrict__ x,
                 const ushort* __restrict__ Wfl, const ushort* __restrict__ Wfr,
                 const float* __restrict__ bias,
                 unsigned char* __restrict__ p8, ushort* __restrict__ q) {
    extern __shared__ char smem[];
    int tid = threadIdx.x;
    if ((int)blockIdx.x >= NSC) {
        ushort* wsm = (ushort*)smem;           // 64KB: Wfl then Wfr fragments
        stage_weights<2 * 128 * 128>(Wfl, Wfr, wsm, tid);
        __syncthreads();
        proj_tile<128, true>((int)blockIdx.x - NSC, tid, x, wsm, wsm + 128 * 128,
                             bias, p8, q, N);
        return;
    }
    unsigned* entry = (unsigned*)smem;                      // [8192] 32KB
    unsigned char* ebkt = (unsigned char*)(entry + CHUNK);  // [8192] 8KB
    int* lhist = (int*)(ebkt + CHUNK);                      // [256]
    int* lbase = lhist + 256;                               // [256]
    int* lcur  = lbase + 256;                               // [256]
    if (tid < 256) lhist[tid] = 0;
    __syncthreads();
    int e0 = blockIdx.x * CHUNK;
    int cnt = min(CHUNK, E - e0);
    int nv = cnt >> 2;
    for (int t = tid; t < nv; t += 512) {
        int4 d4 = ((const int4*)(dst + e0))[t];
        int4 s4 = ((const int4*)(src + e0))[t];
        int i = t * 4;
        int b0 = d4.x >> 9, b1 = d4.y >> 9, b2 = d4.z >> 9, b3 = d4.w >> 9;
        entry[i + 0] = ((unsigned)s4.x << 9) | (unsigned)(d4.x & 511);
        entry[i + 1] = ((unsigned)s4.y << 9) | (unsigned)(d4.y & 511);
        entry[i + 2] = ((unsigned)s4.z << 9) | (unsigned)(d4.z & 511);
        entry[i + 3] = ((unsigned)s4.w << 9) | (unsigned)(d4.w & 511);
        ebkt[i + 0] = (unsigned char)b0; ebkt[i + 1] = (unsigned char)b1;
        ebkt[i + 2] = (unsigned char)b2; ebkt[i + 3] = (unsigned char)b3;
        atomicAdd(&lhist[b0], 1); atomicAdd(&lhist[b1], 1);
        atomicAdd(&lhist[b2], 1); atomicAdd(&lhist[b3], 1);
    }
    for (int i = (nv << 2) + tid; i < cnt; i += 512) {
        int d = dst[e0 + i], s = src[e0 + i];
        int b = d >> 9;
        entry[i] = ((unsigned)s << 9) | (unsigned)(d & 511);
        ebkt[i] = (unsigned char)b;
        atomicAdd(&lhist[b], 1);
    }
    __syncthreads();
    if (tid < 256) {
        int h = lhist[tid];
        lbase[tid] = (h > 0) ? atomicAdd(&bcount[tid], h) : 0;
        lcur[tid] = 0;
    }
    __syncthreads();
    for (int i = tid; i < cnt; i += 512) {
        int b = ebkt[i];
        int o = atomicAdd(&lcur[b], 1);
        bbuf[(long)b * BCAP + lbase[b] + o] = entry[i];
    }
}

// ---------- kc: fused CSR -> agg_relu -> proj2 -> agg_lsm (cooperative) ------------
// 512 threads, 32KB dynamic LDS (CSR arrays / proj2 weights, sequential reuse).
// 3 blocks/CU co-resident (launch_bounds(512,6)); grid-stride loops in each stage.
__global__ void __launch_bounds__(512, 6)
kc_fused(const unsigned* __restrict__ bbuf, const int* __restrict__ bcount,
         int* __restrict__ rsd, float* __restrict__ inv_deg, int* __restrict__ ssrc,
         int NBcsr, int N,
         const unsigned char* __restrict__ p8, const ushort* __restrict__ q,
         ushort* __restrict__ hb,
         const ushort* __restrict__ Wfl2, const ushort* __restrict__ Wfr2,
         const float* __restrict__ bias2,
         unsigned char* __restrict__ u8, ushort* __restrict__ v,
         float* __restrict__ out) {
    extern __shared__ char smem[];
    cg::grid_group gg = cg::this_grid();
    int tid = threadIdx.x;
    int bid = (int)blockIdx.x;
    int G = (int)gridDim.x;
    int wave = tid >> 6, lane = tid & 63;

    // ---- Stage A: build_csr (blocks 0..NBcsr-1; padded lists, sentinel N) ----
    if (bid < NBcsr) {
        int* sdeg = (int*)smem;           // [512]
        int* lcur = sdeg + NPB;           // [512]
        int* wsum = lcur + NPB;           // [8]
        int b = bid;
        int node0 = b * NPB;
        sdeg[tid] = 0;
        __syncthreads();
        int cnt = bcount[b];
        long base = (long)b * BCAP;
        const unsigned* bb = bbuf + base;
        int nv = cnt >> 2;
        for (int t = tid; t < nv; t += 512) {          // uint4-vectorized histogram
            uint4 e = ((const uint4*)bb)[t];
            atomicAdd(&sdeg[e.x & 511], 1);
            atomicAdd(&sdeg[e.y & 511], 1);
            atomicAdd(&sdeg[e.z & 511], 1);
            atomicAdd(&sdeg[e.w & 511], 1);
        }
        for (int i = (nv << 2) + tid; i < cnt; i += 512)
            atomicAdd(&sdeg[bb[i] & 511], 1);
        __syncthreads();
        int c0 = sdeg[tid];
        int dp = (c0 + 15) & ~15;                       // padded degree
        int scan = dp;                                  // wave-shuffle inclusive scan
#pragma unroll
        for (int o = 1; o < 64; o <<= 1) {
            int t = __shfl_up(scan, o);
            if (lane >= o) scan += t;
        }
        if (lane == 63) wsum[wave] = scan;
        __syncthreads();
        int add = 0;
        for (int w = 0; w < wave; ++w) add += wsum[w];
        int rs0 = scan + add - dp;                      // bucket-local excl prefix
        lcur[tid] = rs0;
        if (node0 + tid < N) {
            int2 rv; rv.x = (int)(base + rs0); rv.y = dp;
            *(int2*)(rsd + 2 * (node0 + tid)) = rv;
            inv_deg[node0 + tid] = 1.0f / (float)(c0 > 1 ? c0 : 1);
        }
        __syncthreads();
        for (int t = tid; t < nv; t += 512) {          // uint4-vectorized scatter
            uint4 e = ((const uint4*)bb)[t];
            int p0 = atomicAdd(&lcur[e.x & 511], 1);
            int p1 = atomicAdd(&lcur[e.y & 511], 1);
            int p2 = atomicAdd(&lcur[e.z & 511], 1);
            int p3 = atomicAdd(&lcur[e.w & 511], 1);
            ssrc[base + p0] = (int)(e.x >> 9);
            ssrc[base + p1] = (int)(e.y >> 9);
            ssrc[base + p2] = (int)(e.z >> 9);
            ssrc[base + p3] = (int)(e.w >> 9);
        }
        for (int i = (nv << 2) + tid; i < cnt; i += 512) {
            unsigned w = bb[i];
            int pos = atomicAdd(&lcur[w & 511], 1);
            ssrc[base + pos] = (int)(w >> 9);
        }
        for (int i = c0; i < dp; ++i) ssrc[base + rs0 + i] = N;   // padding fill
        if (tid == 511) {                               // bucket tail for prefetch
            int tot = scan + add;
            for (int k = 0; k < 16; ++k) ssrc[base + tot + k] = N;
        }
    }
    __threadfence();
    gg.sync();

    // ---- Stage B: agg_relu (grid-stride; 1 node/wave, 16 lanes/edge, 8B) ----
    {
        int g = lane >> 4, lm = lane & 15;
        const unsigned char* pb = p8 + lm * 8;
        for (int n = bid * 8 + wave; n < N; n += G * 8) {
            int2 rv2 = *(const int2*)(rsd + 2 * n);
            int start = rv2.x, dp = rv2.y;
            float iv = inv_deg[n];
            uint4 qv = make_uint4(0u, 0u, 0u, 0u);
            if (g == 0) qv = *(const uint4*)(q + (long)n * 128 + lm * 8);
            const int* sp = ssrc + start;
            f32x2 a0 = (f32x2)0.f, a1 = (f32x2)0.f, a2 = (f32x2)0.f, a3 = (f32x2)0.f;
            int4 s = *(const int4*)(sp + 4 * g);
            for (int j = 0; j < dp; j += 16) {
                uint2 v0 = *(const uint2*)(pb + (unsigned)s.x * 128u);
                uint2 v1 = *(const uint2*)(pb + (unsigned)s.y * 128u);
                uint2 v2 = *(const uint2*)(pb + (unsigned)s.z * 128u);
                uint2 v3 = *(const uint2*)(pb + (unsigned)s.w * 128u);
                s = *(const int4*)(sp + j + 16 + 4 * g);
                a0 = pkadd(a0, __builtin_amdgcn_cvt_pk_f32_fp8((int)v0.x, false));
                a1 = pkadd(a1, __builtin_amdgcn_cvt_pk_f32_fp8((int)v0.x, true));
                a2 = pkadd(a2, __builtin_amdgcn_cvt_pk_f32_fp8((int)v0.y, false));
                a3 = pkadd(a3, __builtin_amdgcn_cvt_pk_f32_fp8((int)v0.y, true));
                a0 = pkadd(a0, __builtin_amdgcn_cvt_pk_f32_fp8((int)v1.x, false));
                a1 = pkadd(a1, __builtin_amdgcn_cvt_pk_f32_fp8((int)v1.x, true));
                a2 = pkadd(a2, __builtin_amdgcn_cvt_pk_f32_fp8((int)v1.y, false));
                a3 = pkadd(a3, __builtin_amdgcn_cvt_pk_f32_fp8((int)v1.y, true));
                a0 = pkadd(a0, __builtin_amdgcn_cvt_pk_f32_fp8((int)v2.x, false));
                a1 = pkadd(a1, __builtin_amdgcn_cvt_pk_f32_fp8((int)v2.x, true));
                a2 = pkadd(a2, __builtin_amdgcn_cvt_pk_f32_fp8((int)v2.y, false));
                a3 = pkadd(a3, __builtin_amdgcn_cvt_pk_f32_fp8((int)v2.y, true));
                a0 = pkadd(a0, __builtin_amdgcn_cvt_pk_f32_fp8((int)v3.x, false));
                a1 = pkadd(a1, __builtin_amdgcn_cvt_pk_f32_fp8((int)v3.x, true));
                a2 = pkadd(a2, __builtin_amdgcn_cvt_pk_f32_fp8((int)v3.y, false));
                a3 = pkadd(a3, __builtin_amdgcn_cvt_pk_f32_fp8((int)v3.y, true));
            }
            a0 = pkadd(a0, shflx2(a0, 16)); a1 = pkadd(a1, shflx2(a1, 16));
            a2 = pkadd(a2, shflx2(a2, 16)); a3 = pkadd(a3, shflx2(a3, 16));
            a0 = pkadd(a0, shflx2(a0, 32)); a1 = pkadd(a1, shflx2(a1, 32));
            a2 = pkadd(a2, shflx2(a2, 32)); a3 = pkadd(a3, shflx2(a3, 32));
            if (g == 0) {
                float h0 = fmaxf(a0[0] * iv + bflo(qv.x), 0.f);
                float h1 = fmaxf(a0[1] * iv + bfhi(qv.x), 0.f);
                float h2 = fmaxf(a1[0] * iv + bflo(qv.y), 0.f);
                float h3 = fmaxf(a1[1] * iv + bfhi(qv.y), 0.f);
                float h4 = fmaxf(a2[0] * iv + bflo(qv.z), 0.f);
                float h5 = fmaxf(a2[1] * iv + bfhi(qv.z), 0.f);
                float h6 = fmaxf(a3[0] * iv + bflo(qv.w), 0.f);
                float h7 = fmaxf(a3[1] * iv + bfhi(qv.w), 0.f);
                uint4 hw;
                hw.x = pk4bf(h0, h1); hw.y = pk4bf(h2, h3);
                hw.z = pk4bf(h4, h5); hw.w = pk4bf(h6, h7);
                *(uint4*)(hb + (long)n * 128 + lm * 8) = hw;
            }
        }
    }
    __threadfence();
    gg.sync();

    // ---- Stage C: proj2 (weights staged to LDS, tile-stride) ----
    {
        ushort* wsm = (ushort*)smem;   // 32KB (reuse of CSR region, post-sync)
        stage_weights<2 * 64 * 128>(Wfl2, Wfr2, wsm, tid);
        __syncthreads();
        int NT = (N + 127) / 128;
        for (int t = bid; t < NT; t += G)
            proj_tile<64, false>(t, tid, hb, wsm, wsm + 64 * 128, bias2, u8, v, N);
    }
    __threadfence();
    gg.sync();

    // ---- Stage D: agg_lsm (grid-stride; 1 node/wave, 16 lanes/edge, 4B) ----
    {
        int g = lane >> 4, lm = lane & 15;
        const unsigned char* ub = u8 + lm * 4;
        for (int n = bid * 8 + wave; n < N; n += G * 8) {
            int2 rv2 = *(const int2*)(rsd + 2 * n);
            int start = rv2.x, dp = rv2.y;
            float iv = inv_deg[n];
            uint2 vv2 = *(const uint2*)(v + (long)n * 64 + lm * 4);
            const int* sp = ssrc + start;
            f32x2 a0 = (f32x2)0.f, a1 = (f32x2)0.f;
            int4 s = *(const int4*)(sp + 4 * g);
            for (int j = 0; j < dp; j += 16) {
                unsigned v0 = *(const unsigned*)(ub + (unsigned)s.x * 64u);
                unsigned v1 = *(const unsigned*)(ub + (unsigned)s.y * 64u);
                unsigned v2 = *(const unsigned*)(ub + (unsigned)s.z * 64u);
                unsigned v3 = *(const unsigned*)(ub + (unsigned)s.w * 64u);
                s = *(const int4*)(sp + j + 16 + 4 * g);
                a0 = pkadd(a0, __builtin_amdgcn_cvt_pk_f32_fp8((int)v0, false));
                a1 = pkadd(a1, __builtin_amdgcn_cvt_pk_f32_fp8((int)v0, true));
                a0 = pkadd(a0, __builtin_amdgcn_cvt_pk_f32_fp8((int)v1, false));
                a1 = pkadd(a1, __builtin_amdgcn_cvt_pk_f32_fp8((int)v1, true));
                a0 = pkadd(a0, __builtin_amdgcn_cvt_pk_f32_fp8((int)v2, false));
                a1 = pkadd(a1, __builtin_amdgcn_cvt_pk_f32_fp8((int)v2, true));
                a0 = pkadd(a0, __builtin_amdgcn_cvt_pk_f32_fp8((int)v3, false));
                a1 = pkadd(a1, __builtin_amdgcn_cvt_pk_f32_fp8((int)v3, true));
            }
            a0 = pkadd(a0, shflx2(a0, 16)); a1 = pkadd(a1, shflx2(a1, 16));
            a0 = pkadd(a0, shflx2(a0, 32)); a1 = pkadd(a1, shflx2(a1, 32));

            float z0 = a0[0] * iv + bflo(vv2.x), z1 = a0[1] * iv + bfhi(vv2.x);
            float z2 = a1[0] * iv + bflo(vv2.y), z3 = a1[1] * iv + bfhi(vv2.y);
            float mx = fmaxf(fmaxf(z0, z1), fmaxf(z2, z3));
#pragma unroll
            for (int o = 8; o > 0; o >>= 1) mx = fmaxf(mx, __shfl_xor(mx, o));
            float e = (__expf(z0 - mx) + __expf(z1 - mx)) +
                      (__expf(z2 - mx) + __expf(z3 - mx));
#pragma unroll
            for (int o = 8; o > 0; o >>= 1) e += __shfl_xor(e, o);
            float ls = mx + __logf(e);
            if (g == 0) {
                float4 o0;
                o0.x = z0 - ls; o0.y = z1 - ls; o0.z = z2 - ls; o0.w = z3 - ls;
                *(float4*)(out + (long)n * 64 + lm * 4) = o0;
            }
        }
    }
}

// -----------------------------------------------------------------------------------
extern "C" void kernel_launch(void* const* d_in, const int* in_sizes, int n_in,
                              void* d_out, int out_size, void* d_ws, size_t ws_size,
                              hipStream_t stream) {
    const float* x   = (const float*)d_in[0];
    const int*   ei  = (const int*)d_in[1];
    const float* Wl1 = (const float*)d_in[2];
    const float* Wr1 = (const float*)d_in[3];
    const float* b1  = (const float*)d_in[4];
    const float* Wl2 = (const float*)d_in[5];
    const float* Wr2 = (const float*)d_in[6];
    const float* b2  = (const float*)d_in[7];

    const int N = in_sizes[0] / 128;
    const int E = in_sizes[1] / 2;
    const int* src = ei;
    const int* dst = ei + E;
    const int NB = (N + NPB - 1) / NPB;             // 196 buckets for N=100000
    const int NSC = (E + CHUNK - 1) / CHUNK;        // 196 scatter blocks

    size_t off = 0;
    auto take = [&](size_t nbytes) -> void* {
        void* ptr = (void*)((char*)d_ws + off);
        off += (nbytes + 255) & ~(size_t)255;
        return ptr;
    };
    int*      bcount    = (int*)take((size_t)NB * 4);
    unsigned* bbuf      = (unsigned*)take((size_t)NB * BCAP * 4);   // 12.8 MB
    int*      rsd       = (int*)take((size_t)N * 8);                // {row_start, pdeg}
    float*    inv_deg   = (float*)take((size_t)N * 4);
    int*      ssrc      = (int*)take((size_t)NB * BCAP * 4);        // 12.8 MB (bucket-strided)
    unsigned char* p8   = (unsigned char*)take((size_t)(N + 1) * 128);    // +sentinel row
    ushort*   q         = (ushort*)take((size_t)(N + 1) * 128 * 2);       // +sentinel row
    ushort*   hb        = (ushort*)take((size_t)N * 128 * 2);
    ushort*   Wf_l1     = (ushort*)take(128 * 128 * 2);
    ushort*   Wf_r1     = (ushort*)take(128 * 128 * 2);
    ushort*   Wf_l2     = (ushort*)take(64 * 128 * 2);
    ushort*   Wf_r2     = (ushort*)take(64 * 128 * 2);
    unsigned char* u8 = p8;   // p dead after stage B; stage C rewrites row N = 0
    ushort*        v  = q;    // q dead after stage B
    float*    outp      = (float*)d_out;
    (void)ws_size; (void)n_in; (void)out_size;

    static int coop_grid = 0;
    if (coop_grid == 0) {                           // one-time setup (host-side)
        hipFuncSetAttribute((const void*)k1_scatter_proj1,
                            hipFuncAttributeMaxDynamicSharedMemorySize, 65536);
        hipFuncSetAttribute((const void*)kc_fused,
                            hipFuncAttributeMaxDynamicSharedMemorySize, 65536);
        int nb = 0;
        hipOccupancyMaxActiveBlocksPerMultiprocessor(&nb, (const void*)kc_fused,
                                                     512, 32768);
        hipDeviceProp_t prop{};
        int dev = 0;
        hipGetDevice(&dev);
        hipGetDeviceProperties(&prop, dev);
        int g = nb * prop.multiProcessorCount;
        if (g > 768) g = 768;                       // designed max (3/CU x 256)
        if (g < 256) g = 256;
        coop_grid = g;
    }

    // k0: weight repack + bcount zero
    k0_cvtw<<<96, 512, 0, stream>>>(Wl1, Wr1, Wl2, Wr2, Wf_l1, Wf_r1, Wf_l2, Wf_r2,
                                    bcount, NB);

    // K1: scatter || proj1 (one grid: 196 + 782 blocks)
    int P1 = (N + 127) / 128;
    k1_scatter_proj1<<<NSC + P1, 512, 65536, stream>>>(src, dst, bcount, bbuf,
                                                       E, NSC, N, x,
                                                       Wf_l1, Wf_r1, b1, p8, q);

    // kc: fused CSR -> agg_relu -> proj2 -> agg_lsm (cooperative)
    int NBcsr = NB, n_arg = N;
    void* args[] = { (void*)&bbuf, (void*)&bcount, (void*)&rsd, (void*)&inv_deg,
                     (void*)&ssrc, (void*)&NBcsr, (void*)&n_arg,
                     (void*)&p8, (void*)&q, (void*)&hb,
                     (void*)&Wf_l2, (void*)&Wf_r2, (void*)&b2,
                     (void*)&u8, (void*)&v, (void*)&outp };
    hipLaunchCooperativeKernel((const void*)kc_fused, dim3(coop_grid), dim3(512),
                               args, 32768, stream);
}

// Round 12
// 244.307 us; speedup vs baseline: 2.8388x; 2.8388x over previous
//
#include <hip/hip_runtime.h>
#include <hip/hip_bf16.h>

// GraphSAGE 2-layer, N=100K, E=1.6M, 128->128(relu)->64, log_softmax. fp32 in/out.
//
//   k0: Wf repack + bcount zero
//   k1: bucket_scatter || proj1 (F32IN MFMA, LDS weights)   [r17 form, 46us]
//   k2: build_csr, NPB=128 (782 blocks ~ 3/CU)              <- this round's target
//   agg_relu -> proj2 -> agg_lsm                             (measured-best forms)
//
// r19: REVERT r18 cooperative fusion (694us: grid capped at co-residency destroyed
// agg TLP - each wave serially walked ~16 nodes). r18 closed the accounting: CSR
// alone is ~40-44us (absent from top-5 with 44.9 cutoff) at 196 blocks = 0.77/CU,
// the worst-parallelized stage. Fix: NPB 512->128 (bucket = dst>>7, 782 buckets):
// 4x blocks, 4x less serial work per block. k1 scatter adapts (7-bit local id,
// ushort ebkt, 1024-slot hist = 60KB LDS). BCAP=5120 covers worst-case padding.

typedef __attribute__((ext_vector_type(8))) short short8;   // 8 x bf16 = 4 VGPRs
typedef __attribute__((ext_vector_type(4))) float f32x4;
typedef __attribute__((ext_vector_type(2))) float f32x2;

#define NPB 128          // nodes per bucket (dst >> 7)
#define BCAP 5120        // edge capacity per bucket (padded worst < 4256)
#define CHUNK 8192       // edges per bucket_scatter block

__device__ __forceinline__ ushort f2bf(float f) {           // round-to-nearest-even
    unsigned u = __float_as_uint(f);
    return (ushort)((u + 0x7fff + ((u >> 16) & 1)) >> 16);
}
__device__ __forceinline__ float bflo(unsigned v) { return __uint_as_float(v << 16); }
__device__ __forceinline__ float bfhi(unsigned v) { return __uint_as_float(v & 0xffff0000u); }
__device__ __forceinline__ unsigned pk4bf(float a, float b) {   // 1 VOP3 (RNE)
    unsigned r;
    asm("v_cvt_pk_bf16_f32 %0, %1, %2" : "=v"(r) : "v"(a), "v"(b));
    return r;
}
__device__ __forceinline__ f32x2 pkadd(f32x2 a, f32x2 b) {      // 1 VOP3P (2xf32 add)
    f32x2 r;
    asm("v_pk_add_f32 %0, %1, %2" : "=v"(r) : "v"(a), "v"(b));
    return r;
}
__device__ __forceinline__ f32x2 shflx2(f32x2 v, int m) {
    f32x2 r; r[0] = __shfl_xor(v[0], m); r[1] = __shfl_xor(v[1], m); return r;
}

// ---------- weight repack into MFMA fragment order ---------------------------------
// Wf idx = ((ct*16 + kc)*16 + m)*8 + j holds W[k=kc*8+j][c=ct*16+m]
__device__ __forceinline__ void wfrag_one(const float* W, ushort* Wf, int i, int COLS) {
    int j = i & 7, m = (i >> 3) & 15, kc = (i >> 7) & 15, ct = i >> 11;
    Wf[i] = f2bf(W[(kc * 8 + j) * COLS + ct * 16 + m]);
}

// ---------- k0: weight repack (49152 elements, 96 blocks) + bcount zero ------------
__global__ void __launch_bounds__(512)
k0_cvtw(const float* __restrict__ Wl1, const float* __restrict__ Wr1,
        const float* __restrict__ Wl2, const float* __restrict__ Wr2,
        ushort* __restrict__ Wf_l1, ushort* __restrict__ Wf_r1,
        ushort* __restrict__ Wf_l2, ushort* __restrict__ Wf_r2,
        int* __restrict__ bcount, int NBK) {
    int tid = (int)threadIdx.x;
    if (blockIdx.x == 0)
        for (int i = tid; i < NBK; i += 512) bcount[i] = 0;
    int i = (int)blockIdx.x * 512 + tid;
    if (i < 16384)       wfrag_one(Wl1, Wf_l1, i, 128);
    else if (i < 32768)  wfrag_one(Wr1, Wf_r1, i - 16384, 128);
    else if (i < 40960)  wfrag_one(Wl2, Wf_l2, i - 32768, 64);
    else if (i < 49152)  wfrag_one(Wr2, Wf_r2, i - 40960, 64);
}

// ---------- stage both weight fragment arrays into LDS (linear copy, 512 thr) ------
template <int CTOT>
__device__ __forceinline__ void stage_weights(const ushort* __restrict__ Wfl,
                                              const ushort* __restrict__ Wfr,
                                              ushort* dst, int tid) {
    constexpr int HALF = CTOT / 2;            // ushorts per matrix
    constexpr int ITERS = (CTOT * 2) / 8192;  // 512 thr * 16B per iter
#pragma unroll
    for (int r = 0; r < ITERS; ++r) {
        int u = r * 4096 + tid * 8;           // ushort index; half uniform per r
        const ushort* s = (u < HALF) ? (Wfl + u) : (Wfr + (u - HALF));
        *(short8*)(dst + u) = *(const short8*)s;
    }
}

// ---------- projection tile: p = fp8(X@Wl), q = bf16(X@Wr + b), W already in LDS ---
// Operand-swapped MFMA; 512 threads, 8 waves x 16 rows. Row N = zero sentinel.
template <int COLS, bool F32IN>
__device__ __forceinline__ void proj_tile(int bid, int tid,
                            const void* __restrict__ xin,
                            const ushort* Wl, const ushort* Wr,
                            const float* __restrict__ bias,
                            unsigned char* __restrict__ p8, ushort* __restrict__ q, int N) {
    constexpr int CT = COLS / 16;
    int wave = tid >> 6, lane = tid & 63;
    int quad = lane >> 4, m = lane & 15;
    long row0 = (long)bid * 128 + wave * 16;
    long node = row0 + m;
    long arow = (node < N) ? node : (N - 1);

    f32x4 accp[CT], accq[CT];
#pragma unroll
    for (int ct = 0; ct < CT; ++ct) { accp[ct] = (f32x4)0.0f; accq[ct] = (f32x4)0.0f; }

#pragma unroll
    for (int kk = 0; kk < 128; kk += 32) {
        short8 b;                            // B-frag: B[k][n=lane&15] = x[node][k]
        if (F32IN) {
            const float* xf = (const float*)xin + arow * 128 + kk + quad * 8;
            float4 f0 = *(const float4*)xf;
            float4 f1 = *(const float4*)(xf + 4);
            union { short8 s; unsigned u[4]; } bu;
            bu.u[0] = pk4bf(f0.x, f0.y); bu.u[1] = pk4bf(f0.z, f0.w);
            bu.u[2] = pk4bf(f1.x, f1.y); bu.u[3] = pk4bf(f1.z, f1.w);
            b = bu.s;
        } else {
            b = *(const short8*)((const ushort*)xin + arow * 128 + kk + quad * 8);
        }
        int kc = (kk >> 3) + quad;
#pragma unroll
        for (int ct = 0; ct < CT; ++ct) {
            int boff = ((ct * 16 + kc) * 16 + m) * 8;      // 32-bit LDS addressing
            short8 al = *(const short8*)(Wl + boff);       // ds_read_b128
            short8 ar = *(const short8*)(Wr + boff);
            accp[ct] = __builtin_amdgcn_mfma_f32_16x16x32_bf16(al, b, accp[ct], 0, 0, 0);
            accq[ct] = __builtin_amdgcn_mfma_f32_16x16x32_bf16(ar, b, accq[ct], 0, 0, 0);
        }
    }

    if (node <= N) {                          // row N = zero sentinel
        unsigned msk = (node == N) ? 0u : ~0u;
#pragma unroll
        for (int ct = 0; ct < CT; ++ct) {
            int c0 = ct * 16 + quad * 4;
            float4 bv = *(const float4*)(bias + c0);
            float q0 = accq[ct][0] + bv.x, q1 = accq[ct][1] + bv.y;
            float q2 = accq[ct][2] + bv.z, q3 = accq[ct][3] + bv.w;
            unsigned w = (unsigned)__builtin_amdgcn_cvt_pk_fp8_f32(accp[ct][0], accp[ct][1], 0, false);
            w = (unsigned)__builtin_amdgcn_cvt_pk_fp8_f32(accp[ct][2], accp[ct][3], (int)w, true);
            *(unsigned*)(p8 + node * COLS + c0) = w & msk;
            uint2 qw; qw.x = pk4bf(q0, q1) & msk; qw.y = pk4bf(q2, q3) & msk;
            *(uint2*)(q + node * COLS + c0) = qw;
        }
    }
}

// ---------- K1: bucket_scatter (blocks 0..NSC) || proj1 (rest) ---------------------
// 512 threads, 64KB dynamic LDS. entry=(src<<7)|(dst&127); bucket = dst>>7 (<1024).
__global__ void __launch_bounds__(512, 4)
k1_scatter_proj1(const int* __restrict__ src, const int* __restrict__ dst,
                 int* __restrict__ bcount, unsigned* __restrict__ bbuf,
                 int E, int NSC, int NBK, int N,
                 const float* __restrict__ x,
                 const ushort* __restrict__ Wfl, const ushort* __restrict__ Wfr,
                 const float* __restrict__ bias,
                 unsigned char* __restrict__ p8, ushort* __restrict__ q) {
    extern __shared__ char smem[];
    int tid = threadIdx.x;
    if ((int)blockIdx.x >= NSC) {
        ushort* wsm = (ushort*)smem;           // 64KB: Wfl then Wfr fragments
        stage_weights<2 * 128 * 128>(Wfl, Wfr, wsm, tid);
        __syncthreads();
        proj_tile<128, true>((int)blockIdx.x - NSC, tid, x, wsm, wsm + 128 * 128,
                             bias, p8, q, N);
        return;
    }
    unsigned* entry = (unsigned*)smem;                      // [8192] 32KB
    ushort* ebkt = (ushort*)(entry + CHUNK);                // [8192] 16KB
    int* lhist = (int*)(ebkt + CHUNK);                      // [1024] 4KB
    int* lbase = lhist + 1024;                              // [1024] 4KB
    int* lcur  = lbase + 1024;                              // [1024] 4KB  (60KB total)
    for (int i = tid; i < NBK; i += 512) lhist[i] = 0;
    __syncthreads();
    int e0 = blockIdx.x * CHUNK;
    int cnt = min(CHUNK, E - e0);
    int nv = cnt >> 2;
    for (int t = tid; t < nv; t += 512) {
        int4 d4 = ((const int4*)(dst + e0))[t];
        int4 s4 = ((const int4*)(src + e0))[t];
        int i = t * 4;
        int b0 = d4.x >> 7, b1 = d4.y >> 7, b2 = d4.z >> 7, b3 = d4.w >> 7;
        entry[i + 0] = ((unsigned)s4.x << 7) | (unsigned)(d4.x & 127);
        entry[i + 1] = ((unsigned)s4.y << 7) | (unsigned)(d4.y & 127);
        entry[i + 2] = ((unsigned)s4.z << 7) | (unsigned)(d4.z & 127);
        entry[i + 3] = ((unsigned)s4.w << 7) | (unsigned)(d4.w & 127);
        ebkt[i + 0] = (ushort)b0; ebkt[i + 1] = (ushort)b1;
        ebkt[i + 2] = (ushort)b2; ebkt[i + 3] = (ushort)b3;
        atomicAdd(&lhist[b0], 1); atomicAdd(&lhist[b1], 1);
        atomicAdd(&lhist[b2], 1); atomicAdd(&lhist[b3], 1);
    }
    for (int i = (nv << 2) + tid; i < cnt; i += 512) {
        int d = dst[e0 + i], s = src[e0 + i];
        int b = d >> 7;
        entry[i] = ((unsigned)s << 7) | (unsigned)(d & 127);
        ebkt[i] = (ushort)b;
        atomicAdd(&lhist[b], 1);
    }
    __syncthreads();
    for (int i = tid; i < NBK; i += 512) {
        int h = lhist[i];
        lbase[i] = (h > 0) ? atomicAdd(&bcount[i], h) : 0;
        lcur[i] = 0;
    }
    __syncthreads();
    for (int i = tid; i < cnt; i += 512) {
        int b = ebkt[i];
        int o = atomicAdd(&lcur[b], 1);
        bbuf[(long)b * BCAP + lbase[b] + o] = entry[i];
    }
}

// ---------- K2: build_csr, 128-node buckets (782 blocks ~3/CU) ---------------------
// 512 threads. Histogram 1 pass, 2-wave scan, scatter 1 pass. Padded lists,
// sentinel N, 16-entry bucket tail for agg prefetch overrun.
__global__ void __launch_bounds__(512, 4)
k2_csr(const unsigned* __restrict__ bbuf, const int* __restrict__ bcount,
       int* __restrict__ rsd,            // [2N]: {row_start, padded_deg}
       float* __restrict__ inv_deg, int* __restrict__ ssrc, int N) {
    __shared__ int sdeg[NPB], lcur[NPB], wsum[2];
    int tid = threadIdx.x;
    int lane = tid & 63, wave = tid >> 6;
    int b = blockIdx.x;
    int node0 = b * NPB;
    if (tid < NPB) sdeg[tid] = 0;
    __syncthreads();
    int cnt = bcount[b];
    long base = (long)b * BCAP;
    const unsigned* bb = bbuf + base;
    int nv = cnt >> 2;
    for (int t = tid; t < nv; t += 512) {          // uint4-vectorized histogram
        uint4 e = ((const uint4*)bb)[t];
        atomicAdd(&sdeg[e.x & 127], 1);
        atomicAdd(&sdeg[e.y & 127], 1);
        atomicAdd(&sdeg[e.z & 127], 1);
        atomicAdd(&sdeg[e.w & 127], 1);
    }
    for (int i = (nv << 2) + tid; i < cnt; i += 512)
        atomicAdd(&sdeg[bb[i] & 127], 1);
    __syncthreads();
    int c0 = 0, dp = 0;
    if (tid < NPB) { c0 = sdeg[tid]; dp = (c0 + 15) & ~15; }
    int scan = dp;                                  // wave-shuffle inclusive scan
#pragma unroll
    for (int o = 1; o < 64; o <<= 1) {
        int t = __shfl_up(scan, o);
        if (lane >= o) scan += t;
    }
    if (tid < NPB && lane == 63) wsum[wave] = scan;
    __syncthreads();
    int add = (tid >= 64 && tid < NPB) ? wsum[0] : 0;
    int rs0 = scan + add - dp;                      // bucket-local exclusive prefix
    if (tid < NPB) {
        lcur[tid] = rs0;
        if (node0 + tid < N) {
            int2 rv; rv.x = (int)(base + rs0); rv.y = dp;
            *(int2*)(rsd + 2 * (node0 + tid)) = rv;
            inv_deg[node0 + tid] = 1.0f / (float)(c0 > 1 ? c0 : 1);
        }
    }
    __syncthreads();
    for (int t = tid; t < nv; t += 512) {          // uint4-vectorized scatter
        uint4 e = ((const uint4*)bb)[t];
        int p0 = atomicAdd(&lcur[e.x & 127], 1);
        int p1 = atomicAdd(&lcur[e.y & 127], 1);
        int p2 = atomicAdd(&lcur[e.z & 127], 1);
        int p3 = atomicAdd(&lcur[e.w & 127], 1);
        ssrc[base + p0] = (int)(e.x >> 7);
        ssrc[base + p1] = (int)(e.y >> 7);
        ssrc[base + p2] = (int)(e.z >> 7);
        ssrc[base + p3] = (int)(e.w >> 7);
    }
    for (int i = (nv << 2) + tid; i < cnt; i += 512) {
        unsigned w = bb[i];
        int pos = atomicAdd(&lcur[w & 127], 1);
        ssrc[base + pos] = (int)(w >> 7);
    }
    // padding fill (disjoint from scatter ranges -> no barrier needed)
    if (tid < NPB)
        for (int i = c0; i < dp; ++i) ssrc[base + rs0 + i] = N;
    if (tid == 0) {                                 // bucket tail for prefetch overrun
        __syncthreads();                            // no-op path guard not needed; tid 0 only
    }
    __syncthreads();
    if (tid == 0) {
        int tot = wsum[0] + wsum[1];
        for (int k = 0; k < 16; ++k) ssrc[base + tot + k] = N;
    }
}

// ---------- layer-1 aggregate: h = bf16(relu(mean_nbr(p) + q)) ---------------------
// One wave per node; 16 lanes/edge, 8B/lane, slot g owns 4 consecutive edges.
__global__ void __launch_bounds__(256)
agg_relu_kernel(const unsigned char* __restrict__ p8,  // (N+1) x 128 fp8, row N = 0
                const ushort* __restrict__ q,          // (N+1) x 128 bf16
                const int* __restrict__ ssrc,
                const int* __restrict__ rsd,           // [2N] {row_start, padded_deg}
                const float* __restrict__ inv_deg,
                ushort* __restrict__ hb, int N) {
    int wave = threadIdx.x >> 6, lane = threadIdx.x & 63;
    int n = blockIdx.x * 4 + wave;
    if (n >= N) return;
    int g = lane >> 4, lm = lane & 15;             // 4 edge slots / cols lm*8..lm*8+7
    int2 rv = *(const int2*)(rsd + 2 * n);
    int start = rv.x, dp = rv.y;
    float iv = inv_deg[n];                         // hoisted: hides under gathers
    uint4 qv = make_uint4(0u, 0u, 0u, 0u);
    if (g == 0) qv = *(const uint4*)(q + (long)n * 128 + lm * 8);   // hoisted
    const int* sp = ssrc + start;
    const unsigned char* pb = p8 + lm * 8;
    f32x2 a0 = (f32x2)0.f, a1 = (f32x2)0.f, a2 = (f32x2)0.f, a3 = (f32x2)0.f;
    int4 s = *(const int4*)(sp + 4 * g);           // slot g: edges 4g..4g+3
    for (int j = 0; j < dp; j += 16) {
        uint2 v0 = *(const uint2*)(pb + (unsigned)s.x * 128u);
        uint2 v1 = *(const uint2*)(pb + (unsigned)s.y * 128u);
        uint2 v2 = *(const uint2*)(pb + (unsigned)s.z * 128u);
        uint2 v3 = *(const uint2*)(pb + (unsigned)s.w * 128u);
        s = *(const int4*)(sp + j + 16 + 4 * g);   // prefetch next batch (tail-safe)
        a0 = pkadd(a0, __builtin_amdgcn_cvt_pk_f32_fp8((int)v0.x, false));
        a1 = pkadd(a1, __builtin_amdgcn_cvt_pk_f32_fp8((int)v0.x, true));
        a2 = pkadd(a2, __builtin_amdgcn_cvt_pk_f32_fp8((int)v0.y, false));
        a3 = pkadd(a3, __builtin_amdgcn_cvt_pk_f32_fp8((int)v0.y, true));
        a0 = pkadd(a0, __builtin_amdgcn_cvt_pk_f32_fp8((int)v1.x, false));
        a1 = pkadd(a1, __builtin_amdgcn_cvt_pk_f32_fp8((int)v1.x, true));
        a2 = pkadd(a2, __builtin_amdgcn_cvt_pk_f32_fp8((int)v1.y, false));
        a3 = pkadd(a3, __builtin_amdgcn_cvt_pk_f32_fp8((int)v1.y, true));
        a0 = pkadd(a0, __builtin_amdgcn_cvt_pk_f32_fp8((int)v2.x, false));
        a1 = pkadd(a1, __builtin_amdgcn_cvt_pk_f32_fp8((int)v2.x, true));
        a2 = pkadd(a2, __builtin_amdgcn_cvt_pk_f32_fp8((int)v2.y, false));
        a3 = pkadd(a3, __builtin_amdgcn_cvt_pk_f32_fp8((int)v2.y, true));
        a0 = pkadd(a0, __builtin_amdgcn_cvt_pk_f32_fp8((int)v3.x, false));
        a1 = pkadd(a1, __builtin_amdgcn_cvt_pk_f32_fp8((int)v3.x, true));
        a2 = pkadd(a2, __builtin_amdgcn_cvt_pk_f32_fp8((int)v3.y, false));
        a3 = pkadd(a3, __builtin_amdgcn_cvt_pk_f32_fp8((int)v3.y, true));
    }
    a0 = pkadd(a0, shflx2(a0, 16)); a1 = pkadd(a1, shflx2(a1, 16));
    a2 = pkadd(a2, shflx2(a2, 16)); a3 = pkadd(a3, shflx2(a3, 16));
    a0 = pkadd(a0, shflx2(a0, 32)); a1 = pkadd(a1, shflx2(a1, 32));
    a2 = pkadd(a2, shflx2(a2, 32)); a3 = pkadd(a3, shflx2(a3, 32));
    if (g == 0) {
        float h0 = fmaxf(a0[0] * iv + bflo(qv.x), 0.f);
        float h1 = fmaxf(a0[1] * iv + bfhi(qv.x), 0.f);
        float h2 = fmaxf(a1[0] * iv + bflo(qv.y), 0.f);
        float h3 = fmaxf(a1[1] * iv + bfhi(qv.y), 0.f);
        float h4 = fmaxf(a2[0] * iv + bflo(qv.z), 0.f);
        float h5 = fmaxf(a2[1] * iv + bfhi(qv.z), 0.f);
        float h6 = fmaxf(a3[0] * iv + bflo(qv.w), 0.f);
        float h7 = fmaxf(a3[1] * iv + bfhi(qv.w), 0.f);
        uint4 hw;
        hw.x = pk4bf(h0, h1); hw.y = pk4bf(h2, h3);
        hw.z = pk4bf(h4, h5); hw.w = pk4bf(h6, h7);
        *(uint4*)(hb + (long)n * 128 + lm * 8) = hw;
    }
}

// ---------- proj2 (standalone, 512 threads, 32KB static LDS for weights) -----------
__global__ void __launch_bounds__(512, 4)
proj2_kernel(const ushort* __restrict__ hb,
             const ushort* __restrict__ Wfl, const ushort* __restrict__ Wfr,
             const float* __restrict__ bias,
             unsigned char* __restrict__ u8, ushort* __restrict__ v, int N) {
    __shared__ ushort wsm[2 * 64 * 128];   // 32 KB
    stage_weights<2 * 64 * 128>(Wfl, Wfr, wsm, (int)threadIdx.x);
    __syncthreads();
    proj_tile<64, false>((int)blockIdx.x, (int)threadIdx.x, hb, wsm, wsm + 64 * 128,
                         bias, u8, v, N);
}

// ---------- layer-2 aggregate + log_softmax ----------------------------------------
// One wave per node; 16 lanes/edge, 4B/lane, slot g owns 4 consecutive edges.
__global__ void __launch_bounds__(256)
agg_lsm_kernel(const unsigned char* __restrict__ u8,   // (N+1) x 64 fp8, row N = 0
               const ushort* __restrict__ v,           // (N+1) x 64 bf16
               const int* __restrict__ ssrc,
               const int* __restrict__ rsd,            // [2N] {row_start, padded_deg}
               const float* __restrict__ inv_deg,
               float* __restrict__ out, int N) {
    int wave = threadIdx.x >> 6, lane = threadIdx.x & 63;
    int n = blockIdx.x * 4 + wave;
    if (n >= N) return;
    int g = lane >> 4, lm = lane & 15;             // 4 edge slots / cols lm*4..lm*4+3
    int2 rv = *(const int2*)(rsd + 2 * n);
    int start = rv.x, dp = rv.y;
    float iv = inv_deg[n];                         // hoisted
    uint2 vv2 = *(const uint2*)(v + (long)n * 64 + lm * 4);   // hoisted
    const int* sp = ssrc + start;
    const unsigned char* ub = u8 + lm * 4;
    f32x2 a0 = (f32x2)0.f, a1 = (f32x2)0.f;
    int4 s = *(const int4*)(sp + 4 * g);           // slot g: edges 4g..4g+3
    for (int j = 0; j < dp; j += 16) {
        unsigned v0 = *(const unsigned*)(ub + (unsigned)s.x * 64u);
        unsigned v1 = *(const unsigned*)(ub + (unsigned)s.y * 64u);
        unsigned v2 = *(const unsigned*)(ub + (unsigned)s.z * 64u);
        unsigned v3 = *(const unsigned*)(ub + (unsigned)s.w * 64u);
        s = *(const int4*)(sp + j + 16 + 4 * g);   // prefetch next batch (tail-safe)
        a0 = pkadd(a0, __builtin_amdgcn_cvt_pk_f32_fp8((int)v0, false));
        a1 = pkadd(a1, __builtin_amdgcn_cvt_pk_f32_fp8((int)v0, true));
        a0 = pkadd(a0, __builtin_amdgcn_cvt_pk_f32_fp8((int)v1, false));
        a1 = pkadd(a1, __builtin_amdgcn_cvt_pk_f32_fp8((int)v1, true));
        a0 = pkadd(a0, __builtin_amdgcn_cvt_pk_f32_fp8((int)v2, false));
        a1 = pkadd(a1, __builtin_amdgcn_cvt_pk_f32_fp8((int)v2, true));
        a0 = pkadd(a0, __builtin_amdgcn_cvt_pk_f32_fp8((int)v3, false));
        a1 = pkadd(a1, __builtin_amdgcn_cvt_pk_f32_fp8((int)v3, true));
    }
    a0 = pkadd(a0, shflx2(a0, 16)); a1 = pkadd(a1, shflx2(a1, 16));
    a0 = pkadd(a0, shflx2(a0, 32)); a1 = pkadd(a1, shflx2(a1, 32));

    float z0 = a0[0] * iv + bflo(vv2.x), z1 = a0[1] * iv + bfhi(vv2.x);
    float z2 = a1[0] * iv + bflo(vv2.y), z3 = a1[1] * iv + bfhi(vv2.y);
    float mx = fmaxf(fmaxf(z0, z1), fmaxf(z2, z3));
#pragma unroll
    for (int o = 8; o > 0; o >>= 1) mx = fmaxf(mx, __shfl_xor(mx, o));   // over lm bits
    float e = (__expf(z0 - mx) + __expf(z1 - mx)) + (__expf(z2 - mx) + __expf(z3 - mx));
#pragma unroll
    for (int o = 8; o > 0; o >>= 1) e += __shfl_xor(e, o);
    float ls = mx + __logf(e);
    if (g == 0) {                                  // 16 lanes store 4 floats each
        float4 o0;
        o0.x = z0 - ls; o0.y = z1 - ls; o0.z = z2 - ls; o0.w = z3 - ls;
        *(float4*)(out + (long)n * 64 + lm * 4) = o0;
    }
}

// -----------------------------------------------------------------------------------
extern "C" void kernel_launch(void* const* d_in, const int* in_sizes, int n_in,
                              void* d_out, int out_size, void* d_ws, size_t ws_size,
                              hipStream_t stream) {
    const float* x   = (const float*)d_in[0];
    const int*   ei  = (const int*)d_in[1];
    const float* Wl1 = (const float*)d_in[2];
    const float* Wr1 = (const float*)d_in[3];
    const float* b1  = (const float*)d_in[4];
    const float* Wl2 = (const float*)d_in[5];
    const float* Wr2 = (const float*)d_in[6];
    const float* b2  = (const float*)d_in[7];

    const int N = in_sizes[0] / 128;
    const int E = in_sizes[1] / 2;
    const int* src = ei;
    const int* dst = ei + E;
    const int NBK = (N + NPB - 1) / NPB;            // 782 buckets for N=100000
    const int NSC = (E + CHUNK - 1) / CHUNK;        // 196 scatter blocks

    size_t off = 0;
    auto take = [&](size_t nbytes) -> void* {
        void* ptr = (void*)((char*)d_ws + off);
        off += (nbytes + 255) & ~(size_t)255;
        return ptr;
    };
    int*      bcount    = (int*)take((size_t)NBK * 4);
    unsigned* bbuf      = (unsigned*)take((size_t)NBK * BCAP * 4);  // 16 MB
    int*      rsd       = (int*)take((size_t)N * 8);                // {row_start, pdeg}
    float*    inv_deg   = (float*)take((size_t)N * 4);
    int*      ssrc      = (int*)take((size_t)NBK * BCAP * 4);       // 16 MB
    unsigned char* p8   = (unsigned char*)take((size_t)(N + 1) * 128);    // +sentinel row
    ushort*   q         = (ushort*)take((size_t)(N + 1) * 128 * 2);       // +sentinel row
    ushort*   hb        = (ushort*)take((size_t)N * 128 * 2);
    ushort*   Wf_l1     = (ushort*)take(128 * 128 * 2);
    ushort*   Wf_r1     = (ushort*)take(128 * 128 * 2);
    ushort*   Wf_l2     = (ushort*)take(64 * 128 * 2);
    ushort*   Wf_r2     = (ushort*)take(64 * 128 * 2);
    unsigned char* u8 = p8;   // p dead after agg_relu; proj2 rewrites row N = 0
    ushort*        v  = q;    // q dead after agg_relu
    (void)ws_size; (void)n_in; (void)out_size;

    static bool attr_set = false;                   // allow 64KB dynamic LDS
    if (!attr_set) {
        hipFuncSetAttribute((const void*)k1_scatter_proj1,
                            hipFuncAttributeMaxDynamicSharedMemorySize, 65536);
        attr_set = true;
    }

    // k0: weight repack + bcount zero
    k0_cvtw<<<96, 512, 0, stream>>>(Wl1, Wr1, Wl2, Wr2, Wf_l1, Wf_r1, Wf_l2, Wf_r2,
                                    bcount, NBK);

    // K1: scatter || proj1 (one grid: 196 + 782 blocks)
    int P1 = (N + 127) / 128;
    k1_scatter_proj1<<<NSC + P1, 512, 65536, stream>>>(src, dst, bcount, bbuf,
                                                       E, NSC, NBK, N, x,
                                                       Wf_l1, Wf_r1, b1, p8, q);

    // K2: CSR, 128-node buckets (782 blocks)
    k2_csr<<<NBK, 512, 0, stream>>>(bbuf, bcount, rsd, inv_deg, ssrc, N);

    // layer 1 aggregate
    agg_relu_kernel<<<(N + 3) / 4, 256, 0, stream>>>(p8, q, ssrc, rsd, inv_deg, hb, N);

    // layer 2
    proj2_kernel<<<(N + 127) / 128, 512, 0, stream>>>(hb, Wf_l2, Wf_r2, b2, u8, v, N);
    agg_lsm_kernel<<<(N + 3) / 4, 256, 0, stream>>>(u8, v, ssrc, rsd, inv_deg,
                                                    (float*)d_out, N);
}